// Round 1
// baseline (1595.129 us; speedup 1.0000x reference)
//
#include <hip/hip_runtime.h>
#include <math.h>

#define T_LEN 1016

// ---------------- Kernel A: mu-law encode + q output + embedding ----------------
__global__ void k_mulaw_embed(const float* __restrict__ audio,
                              const float* __restrict__ embed,
                              float* __restrict__ x0,
                              float* __restrict__ q_out)
{
    int t = blockIdx.x * blockDim.x + threadIdx.x;
    if (t >= T_LEN) return;
    float x = audio[t];
    x = fminf(1.f, fmaxf(-1.f, x));
    float ax = fabsf(x);
    float sg = (x > 0.f) ? 1.f : ((x < 0.f) ? -1.f : 0.f);
    float m = sg * log1pf(255.f * ax) / log1pf(255.f);
    float v = (m + 1.f) * 0.5f * 255.f + 0.5f;
    v = fminf(255.f, fmaxf(0.f, v));
    int q = (int)v;               // trunc == floor for positives
    q_out[t] = (float)q;
    const float* e = embed + q * 64;
    for (int c = 0; c < 64; ++c) x0[(size_t)c * T_LEN + t] = e[c];
}

// ---------------- Kernel B: conv_transpose upsample (cropped) ----------------
// cond0[o, oct*8+ph] = b_up[o] + sum_cin f[cin,oct]*W[cin,o,8+ph] + f[cin,oct+1]*W[cin,o,ph]
// Block: 8 c_out, all 1016 t.  512 threads: ty=tid>>6 (c_out), tx=tid&63 (octave group).
__global__ __launch_bounds__(512) void k_upsample(
    const float* __restrict__ F,     // [2048][128]
    const float* __restrict__ W,     // [2048][2048][16]
    const float* __restrict__ b_up,  // [2048]
    float* __restrict__ out)         // [2048][1016]
{
    __shared__ float fs[8][128];
    __shared__ float wsm[8][128];   // [ci][co*16 + kap]
    const int tid = threadIdx.x;
    const int cob = blockIdx.x * 8;
    const int tx = tid & 63;
    const int ty = tid >> 6;

    float acc[2][8];
    #pragma unroll
    for (int a = 0; a < 2; ++a)
        #pragma unroll
        for (int b = 0; b < 8; ++b) acc[a][b] = 0.f;

    for (int cc = 0; cc < 2048; cc += 8) {
        __syncthreads();
        int flat = tid * 4;
        if (flat < 1024) {
            int ci = flat >> 7, r = flat & 127;
            *(float4*)&fs[ci][r] = *(const float4*)&F[(size_t)(cc + ci) * 128 + r];
        } else {
            int f2 = flat - 1024;
            int ci = f2 >> 7, r = f2 & 127;   // r = co*16 + kap, kap%4==0
            *(float4*)&wsm[ci][r] =
                *(const float4*)&W[(size_t)(cc + ci) * 32768 + (size_t)(cob + (r >> 4)) * 16 + (r & 15)];
        }
        __syncthreads();
        #pragma unroll
        for (int ci = 0; ci < 8; ++ci) {
            float wr[16];
            #pragma unroll
            for (int k = 0; k < 16; ++k) wr[k] = wsm[ci][ty * 16 + k];
            #pragma unroll
            for (int oi = 0; oi < 2; ++oi) {
                int o = tx + oi * 64;
                if (o < 127) {
                    float f0 = fs[ci][o], f1 = fs[ci][o + 1];
                    #pragma unroll
                    for (int ph = 0; ph < 8; ++ph)
                        acc[oi][ph] += f0 * wr[8 + ph] + f1 * wr[ph];
                }
            }
        }
    }
    float bb = b_up[cob + ty];
    #pragma unroll
    for (int oi = 0; oi < 2; ++oi) {
        int o = tx + oi * 64;
        if (o < 127) {
            #pragma unroll
            for (int ph = 0; ph < 8; ++ph)
                out[(size_t)(cob + ty) * T_LEN + o * 8 + ph] = acc[oi][ph] + bb;
        }
    }
}

// ---------------- Generic fp32 GEMM: Y = (relu?)(W @ X + bias), optional shifted store ----------------
// W: [M][K] row-major, X: [K][N], Y: [M][N].  64x64 tile, BK=16, 256 threads, 4x4 per thread.
template<bool RELU_IN, bool RELU_OUT, bool SHIFT>
__global__ __launch_bounds__(256) void gemm_f32(
    const float* __restrict__ W, const float* __restrict__ X,
    const float* __restrict__ bias, float* __restrict__ Y,
    int M, int K, int N)
{
    __shared__ float ws_s[16][68];
    __shared__ float xs_s[16][68];
    const int m0 = blockIdx.y * 64;
    const int n0 = blockIdx.x * 64;
    const int tid = threadIdx.x;
    const int tx = tid & 15, ty = tid >> 4;

    float acc[4][4];
    #pragma unroll
    for (int i = 0; i < 4; ++i)
        #pragma unroll
        for (int j = 0; j < 4; ++j) acc[i][j] = 0.f;

    for (int kk = 0; kk < K; kk += 16) {
        {   // W tile -> ws_s[k][m]
            int m = tid >> 2;
            int k4 = (tid & 3) * 4;
            float4 v = *(const float4*)&W[(size_t)(m0 + m) * K + kk + k4];
            ws_s[k4 + 0][m] = v.x; ws_s[k4 + 1][m] = v.y;
            ws_s[k4 + 2][m] = v.z; ws_s[k4 + 3][m] = v.w;
        }
        {   // X tile -> xs_s[k][n]
            int k = tid >> 4;
            int n4 = (tid & 15) * 4;
            int n = n0 + n4;
            float4 v;
            if (n + 3 < N) v = *(const float4*)&X[(size_t)(kk + k) * N + n];
            else {
                v.x = (n + 0 < N) ? X[(size_t)(kk + k) * N + n + 0] : 0.f;
                v.y = (n + 1 < N) ? X[(size_t)(kk + k) * N + n + 1] : 0.f;
                v.z = (n + 2 < N) ? X[(size_t)(kk + k) * N + n + 2] : 0.f;
                v.w = (n + 3 < N) ? X[(size_t)(kk + k) * N + n + 3] : 0.f;
            }
            if (RELU_IN) {
                v.x = fmaxf(v.x, 0.f); v.y = fmaxf(v.y, 0.f);
                v.z = fmaxf(v.z, 0.f); v.w = fmaxf(v.w, 0.f);
            }
            *(float4*)&xs_s[k][n4] = v;
        }
        __syncthreads();
        #pragma unroll
        for (int k = 0; k < 16; ++k) {
            float a[4], b[4];
            #pragma unroll
            for (int i = 0; i < 4; ++i) a[i] = ws_s[k][ty * 4 + i];
            #pragma unroll
            for (int j = 0; j < 4; ++j) b[j] = xs_s[k][tx * 4 + j];
            #pragma unroll
            for (int i = 0; i < 4; ++i)
                #pragma unroll
                for (int j = 0; j < 4; ++j) acc[i][j] += a[i] * b[j];
        }
        __syncthreads();
    }
    #pragma unroll
    for (int i = 0; i < 4; ++i) {
        int m = m0 + ty * 4 + i;
        float bb = bias ? bias[m] : 0.f;
        #pragma unroll
        for (int j = 0; j < 4; ++j) {
            int n = n0 + tx * 4 + j;
            float v = acc[i][j] + bb;
            if (RELU_OUT) v = fmaxf(v, 0.f);
            if (!SHIFT) {
                if (n < N) Y[(size_t)m * N + n] = v;
            } else {
                if (n == 0) Y[(size_t)m * N] = 0.f;
                if (n + 1 < N) Y[(size_t)m * N + n + 1] = v;
            }
        }
    }
}

// ---------------- Layer kernel: dilated gated conv + res + skip ----------------
__global__ __launch_bounds__(256) void k_layer(
    const float* __restrict__ x_in,   // [64][1016]
    float* __restrict__ x_out,        // [64][1016]
    const float* __restrict__ cond,   // [128][1016] slice for this layer
    const float* __restrict__ w_dil,  // [128][64][2]
    const float* __restrict__ b_dil,  // [128]
    const float* __restrict__ w_res,  // [64][64] (null for last)
    const float* __restrict__ b_res,  // [64]
    const float* __restrict__ w_skip, // [256][64]
    const float* __restrict__ b_skip, // [256]
    float* __restrict__ skip_acc,     // [256][1016]
    int d, int first, int last)
{
    __shared__ float xs[64 * 136];
    __shared__ float ia_s[128 * 9];
    __shared__ float acts_s[64 * 9];
    const int tid = threadIdx.x;
    const int t0 = blockIdx.x * 8;
    const int w = 8 + d;

    // stage x window [t0-d, t0+8)
    int count = 64 * w;
    for (int idx = tid; idx < count; idx += 256) {
        int c = idx / w, tt = idx - c * w;
        int tg = t0 - d + tt;
        xs[idx] = (tg >= 0) ? x_in[(size_t)c * T_LEN + tg] : 0.f;
    }
    __syncthreads();

    // ia[o][t] for o in [0,128), t in [0,8)
    {
        int o = tid & 127;
        int tq = tid >> 7;
        float ia[4];
        #pragma unroll
        for (int s = 0; s < 4; ++s) {
            int t = tq + 2 * s;
            ia[s] = b_dil[o] + cond[(size_t)o * T_LEN + t0 + t];
        }
        const float* wd = w_dil + (size_t)o * 128;
        for (int c = 0; c < 64; ++c) {
            float w0 = wd[c * 2], w1 = wd[c * 2 + 1];
            const float* xr = xs + c * w;
            #pragma unroll
            for (int s = 0; s < 4; ++s) {
                int t = tq + 2 * s;
                ia[s] += w0 * xr[t] + w1 * xr[t + d];
            }
        }
        #pragma unroll
        for (int s = 0; s < 4; ++s) {
            int t = tq + 2 * s;
            ia_s[o * 9 + t] = ia[s];
        }
    }
    __syncthreads();

    // gated activations: acts[c][t], c in [0,64)
    #pragma unroll
    for (int rep = 0; rep < 2; ++rep) {
        int idx = tid + rep * 256;      // 0..511
        int c = idx >> 3, t = idx & 7;
        float a = ia_s[c * 9 + t];
        float g = ia_s[(c + 64) * 9 + t];
        acts_s[c * 9 + t] = tanhf(a) * (1.f / (1.f + expf(-g)));
    }
    __syncthreads();

    // skip: o = tid in [0,256)
    {
        int o = tid;
        float acc[8];
        #pragma unroll
        for (int t = 0; t < 8; ++t) acc[t] = 0.f;
        const float* wk = w_skip + (size_t)o * 64;
        for (int c = 0; c < 64; ++c) {
            float wv = wk[c];
            #pragma unroll
            for (int t = 0; t < 8; ++t) acc[t] += wv * acts_s[c * 9 + t];
        }
        float bb = b_skip[o];
        #pragma unroll
        for (int t = 0; t < 8; ++t) {
            size_t oidx = (size_t)o * T_LEN + t0 + t;
            float prev = first ? 0.f : skip_acc[oidx];
            skip_acc[oidx] = prev + acc[t] + bb;
        }
    }

    // res + x update (skip on last layer)
    if (!last) {
        #pragma unroll
        for (int rep = 0; rep < 2; ++rep) {
            int idx = tid + rep * 256;
            int c = idx >> 3, t = idx & 7;
            float r = b_res[c];
            const float* wr = w_res + (size_t)c * 64;
            for (int cc = 0; cc < 64; ++cc) r += wr[cc] * acts_s[cc * 9 + t];
            x_out[(size_t)c * T_LEN + t0 + t] = r + xs[c * w + t + d];
        }
    }
}

// ---------------- host launch ----------------
extern "C" void kernel_launch(void* const* d_in, const int* in_sizes, int n_in,
                              void* d_out, int out_size, void* d_ws, size_t ws_size,
                              hipStream_t stream)
{
    const float* features = (const float*)d_in[0];
    const float* audio    = (const float*)d_in[1];
    const float* w_up     = (const float*)d_in[2];
    const float* b_up     = (const float*)d_in[3];
    const float* w_cond   = (const float*)d_in[4];
    const float* b_cond   = (const float*)d_in[5];
    const float* embed    = (const float*)d_in[6];
    const float* w_dil    = (const float*)d_in[7];
    const float* b_dil    = (const float*)d_in[8];
    const float* w_res    = (const float*)d_in[9];
    const float* b_res    = (const float*)d_in[10];
    const float* w_skip   = (const float*)d_in[11];
    const float* b_skip   = (const float*)d_in[12];
    const float* w_out    = (const float*)d_in[13];
    const float* w_end    = (const float*)d_in[14];
    float* out = (float*)d_out;

    float* ws    = (float*)d_ws;
    float* x0    = ws;                    // 64*1016
    float* x1    = x0 + 65024;            // 64*1016
    float* condA = x1 + 65024;            // 2048*1016
    float* condB = condA + 2080768;       // 2048*1016
    float* skip  = condB + 2080768;       // 256*1016
    float* h2    = skip + 260096;         // 256*1016

    // 1. mu-law + q + embedding
    k_mulaw_embed<<<4, 256, 0, stream>>>(audio, embed, x0, out + 260096);
    // 2. upsample conv-transpose -> condA
    k_upsample<<<256, 512, 0, stream>>>(features, w_up, b_up, condA);
    // 3. condB = w_cond @ condA + b_cond
    gemm_f32<false, false, false><<<dim3(16, 32), 256, 0, stream>>>(
        w_cond, condA, b_cond, condB, 2048, 2048, T_LEN);
    // 4. cond_acts = w_cond @ condB + b_cond  (into condA)
    gemm_f32<false, false, false><<<dim3(16, 32), 256, 0, stream>>>(
        w_cond, condB, b_cond, condA, 2048, 2048, T_LEN);

    // 5. 16 WaveNet layers (sequential)
    float* xbuf[2] = {x0, x1};
    for (int i = 0; i < 16; ++i) {
        int d = 1 << (i & 7);
        k_layer<<<127, 256, 0, stream>>>(
            xbuf[i & 1], xbuf[(i + 1) & 1],
            condA + (size_t)i * 128 * T_LEN,
            w_dil + (size_t)i * 16384, b_dil + i * 128,
            (i < 15) ? (w_res + (size_t)i * 4096) : (const float*)nullptr,
            (i < 15) ? (b_res + i * 64) : (const float*)nullptr,
            w_skip + (size_t)i * 16384, b_skip + i * 256,
            skip, d, (i == 0) ? 1 : 0, (i == 15) ? 1 : 0);
    }

    // 6. h2 = relu(w_out @ relu(skip))
    gemm_f32<true, true, false><<<dim3(16, 4), 256, 0, stream>>>(
        w_out, skip, nullptr, h2, 256, 256, T_LEN);
    // 7. out = shift(w_end @ h2)
    gemm_f32<false, false, true><<<dim3(16, 4), 256, 0, stream>>>(
        w_end, h2, nullptr, out, 256, 256, T_LEN);
}

// Round 4
// 1009.303 us; speedup vs baseline: 1.5804x; 1.5804x over previous
//
#include <hip/hip_runtime.h>
#include <math.h>

#define T_LEN 1016

typedef __attribute__((ext_vector_type(8))) short bf16x8;
typedef __attribute__((ext_vector_type(4))) float f32x4;
typedef __attribute__((ext_vector_type(4))) unsigned int uint4v;
typedef __attribute__((ext_vector_type(2))) unsigned int uint2v;

static __device__ __forceinline__ unsigned pk_bf16(float lo, float hi) {
    unsigned r;
    asm("v_cvt_pk_bf16_f32 %0, %1, %2" : "=v"(r) : "v"(lo), "v"(hi));
    return r;
}

#define F4C(v, i) ((i) == 0 ? (v).x : (i) == 1 ? (v).y : (i) == 2 ? (v).z : (v).w)

// ---------------- Kernel A: mu-law encode + q output + embedding ----------------
__global__ void k_mulaw_embed(const float* __restrict__ audio,
                              const float* __restrict__ embed,
                              float* __restrict__ x0,
                              float* __restrict__ q_out)
{
    int t = blockIdx.x * blockDim.x + threadIdx.x;
    if (t >= T_LEN) return;
    float x = audio[t];
    x = fminf(1.f, fmaxf(-1.f, x));
    float ax = fabsf(x);
    float sg = (x > 0.f) ? 1.f : ((x < 0.f) ? -1.f : 0.f);
    float m = sg * log1pf(255.f * ax) / log1pf(255.f);
    float v = (m + 1.f) * 0.5f * 255.f + 0.5f;
    v = fminf(255.f, fmaxf(0.f, v));
    int q = (int)v;
    q_out[t] = (float)q;
    const float* e = embed + q * 64;
    for (int c = 0; c < 64; ++c) x0[(size_t)c * T_LEN + t] = e[c];
}

// ---------------- fp32 -> bf16 convert (w_cond) ----------------
__global__ __launch_bounds__(256) void k_cvt_bf16(const float* __restrict__ src,
                                                  unsigned short* __restrict__ dst)
{
    int i4 = (blockIdx.x * 256 + threadIdx.x) * 4;
    float4 v = *(const float4*)&src[i4];
    uint2v p;
    p.x = pk_bf16(v.x, v.y);
    p.y = pk_bf16(v.z, v.w);
    *(uint2v*)&dst[i4] = p;
}

// ---------------- build F2T[oct][2c+tap] bf16 : interleaved feature matrix ----------------
// F2T[oct][2c]   = f[c][oct]     (pairs with W[c,o,8+ph])
// F2T[oct][2c+1] = f[c][oct+1]   (pairs with W[c,o,ph])
// row 127 zeroed (pad column of the GEMM)
__global__ __launch_bounds__(256) void k_build_f2t(const float* __restrict__ F,
                                                   unsigned short* __restrict__ f2t)
{
    int oct = blockIdx.x;             // 0..127
    for (int c = threadIdx.x; c < 2048; c += 256) {
        float v0 = (oct < 127) ? F[(size_t)c * 128 + oct] : 0.f;
        float v1 = (oct < 127) ? F[(size_t)c * 128 + oct + 1] : 0.f;
        *(unsigned*)&f2t[(size_t)oct * 4096 + 2 * c] = pk_bf16(v0, v1);
    }
}

// ---------------- MFMA upsample ----------------
// out[(o,ph), oct] = b_up[o] + sum_{cin2} A[(o,ph)][cin2] * F2[cin2][oct]
// A[(o,ph)][2c]   = W[c][o][8+ph],  A[(o,ph)][2c+1] = W[c][o][ph]
// M=16384 (o*8+ph), N=128 (oct; col 127 pad), K=4096 (cin2)
// Block: 8 c_out (BM=64), 4 waves (2m x 2n), BK=64, reg-staged dbuf LDS.
__global__ __launch_bounds__(256) void k_upsample_mfma(
    const unsigned short* __restrict__ f2t,  // [128][4096] bf16
    const float* __restrict__ W,             // [2048][2048][16] f32
    const float* __restrict__ b_up,          // [2048]
    unsigned short* __restrict__ cond0)      // [2048][1024] bf16
{
    __shared__ char lds_raw[49152];   // As: 2 x 8KB @0, Bs: 2 x 16KB @16384

    const int tid  = threadIdx.x;
    const int wave = tid >> 6;
    const int lane = tid & 63;
    const int ob   = blockIdx.x * 8;   // c_out base
    const int wm = wave & 1, wn = wave >> 1;
    const int row = lane & 15, g = lane >> 4;

    // ---- precomputed A-staging maps (j = 0..1) ----
    int cj[2], wbyte[2][4];
    size_t aWoff[2];
    #pragma unroll
    for (int j = 0; j < 2; ++j) {
        int flat = j * 256 + tid;          // [0,512)
        int cp = flat >> 4;                // c' 0..31
        int op = (flat >> 1) & 7;          // o' 0..7
        int h  = flat & 1;
        cj[j] = cp;
        aWoff[j] = (size_t)cp * 32768 + (size_t)(ob + op) * 16 + h * 4;
        #pragma unroll
        for (int i = 0; i < 4; ++i) {
            int ph = h * 4 + i;
            int m  = op * 8 + ph;
            wbyte[j][i] = m * 128 + ((cp * 4) ^ (ph << 4));
        }
    }
    // ---- B-staging maps ----
    const int bn = tid >> 1, bhalf = tid & 1;
    int bSrc[4], bbw[4];
    #pragma unroll
    for (int q = 0; q < 4; ++q) {
        bSrc[q] = bn * 4096 + bhalf * 32 + q * 8;
        bbw[q]  = bn * 128 + ((((bhalf * 4 + q) * 16)) ^ ((bn & 7) << 4));
    }
    // ---- compute-fragment LDS addresses ----
    int abyte[2][2], bbyte[2][4];
    #pragma unroll
    for (int s = 0; s < 2; ++s) {
        #pragma unroll
        for (int fm = 0; fm < 2; ++fm) {
            int m = wm * 32 + fm * 16 + row;
            abyte[s][fm] = m * 128 + (((s * 4 + g) * 16) ^ ((m & 7) << 4));
        }
        #pragma unroll
        for (int fn = 0; fn < 4; ++fn) {
            int n = wn * 64 + fn * 16 + row;
            bbyte[s][fn] = n * 128 + (((s * 4 + g) * 16) ^ ((n & 7) << 4));
        }
    }

    f32x4 acc[2][4];
    #pragma unroll
    for (int a = 0; a < 2; ++a)
        #pragma unroll
        for (int b = 0; b < 4; ++b) acc[a][b] = (f32x4){0.f, 0.f, 0.f, 0.f};

    float4 aL[2], aH[2];
    uint4v bstg[4];

    // ---- prologue: stage round 0 ----
    #pragma unroll
    for (int j = 0; j < 2; ++j) {
        const float* p = W + aWoff[j];
        aL[j] = *(const float4*)p;
        aH[j] = *(const float4*)(p + 8);
    }
    #pragma unroll
    for (int q = 0; q < 4; ++q)
        bstg[q] = *(const uint4v*)(f2t + bSrc[q]);
    #pragma unroll
    for (int j = 0; j < 2; ++j)
        #pragma unroll
        for (int i = 0; i < 4; ++i)
            *(unsigned*)(lds_raw + wbyte[j][i]) = pk_bf16(F4C(aH[j], i), F4C(aL[j], i));
    #pragma unroll
    for (int q = 0; q < 4; ++q)
        *(uint4v*)(lds_raw + 16384 + bbw[q]) = bstg[q];
    __syncthreads();

    int cur = 0;
    for (int r = 0; r < 64; ++r) {
        const bool more = (r < 63);
        if (more) {
            const size_t roff = (size_t)(r + 1) * (32 * 32768);
            #pragma unroll
            for (int j = 0; j < 2; ++j) {
                const float* p = W + aWoff[j] + roff;
                aL[j] = *(const float4*)p;
                aH[j] = *(const float4*)(p + 8);
            }
            const int bo = (r + 1) * 64;
            #pragma unroll
            for (int q = 0; q < 4; ++q)
                bstg[q] = *(const uint4v*)(f2t + bSrc[q] + bo);
        }
        // compute from LDS[cur]
        {
            const char* As = lds_raw + cur * 8192;
            const char* Bs = lds_raw + 16384 + cur * 16384;
            #pragma unroll
            for (int s = 0; s < 2; ++s) {
                bf16x8 af[2];
                #pragma unroll
                for (int fm = 0; fm < 2; ++fm)
                    af[fm] = *(const bf16x8*)(As + abyte[s][fm]);
                #pragma unroll
                for (int fn = 0; fn < 4; ++fn) {
                    bf16x8 bf = *(const bf16x8*)(Bs + bbyte[s][fn]);
                    acc[0][fn] = __builtin_amdgcn_mfma_f32_16x16x32_bf16(af[0], bf, acc[0][fn], 0, 0, 0);
                    acc[1][fn] = __builtin_amdgcn_mfma_f32_16x16x32_bf16(af[1], bf, acc[1][fn], 0, 0, 0);
                }
            }
        }
        if (more) {
            char* As = lds_raw + (cur ^ 1) * 8192;
            char* Bs = lds_raw + 16384 + (cur ^ 1) * 16384;
            #pragma unroll
            for (int j = 0; j < 2; ++j)
                #pragma unroll
                for (int i = 0; i < 4; ++i)
                    *(unsigned*)(As + wbyte[j][i]) = pk_bf16(F4C(aH[j], i), F4C(aL[j], i));
            #pragma unroll
            for (int q = 0; q < 4; ++q)
                *(uint4v*)(Bs + bbw[q]) = bstg[q];
        }
        __syncthreads();
        cur ^= 1;
    }

    // ---- epilogue: bias + bf16 pack + coalesced b64 stores ----
    #pragma unroll
    for (int fm = 0; fm < 2; ++fm) {
        const int och = ob + wm * 4 + fm * 2 + (g >> 1);
        const int ph0 = (g & 1) * 4;
        const float bb = b_up[och];
        #pragma unroll
        for (int fn = 0; fn < 4; ++fn) {
            const int oct = wn * 64 + fn * 16 + row;
            if (oct == 127) continue;
            float v0 = acc[fm][fn].x + bb;
            float v1 = acc[fm][fn].y + bb;
            float v2 = acc[fm][fn].z + bb;
            float v3 = acc[fm][fn].w + bb;
            uint2v pkd;
            pkd.x = pk_bf16(v0, v1);
            pkd.y = pk_bf16(v2, v3);
            *(uint2v*)&cond0[(size_t)och * 1024 + oct * 8 + ph0] = pkd;
        }
    }
}

// ---------------- bf16 transpose: cond0[2048][1024] -> cond0T[1024][2048], rows>=1016 zero ----
__global__ __launch_bounds__(256) void k_transpose_bf16(const unsigned short* __restrict__ src,
                                                        unsigned short* __restrict__ dst)
{
    __shared__ unsigned short sm[64][68];
    const int t0 = blockIdx.x * 64, o0 = blockIdx.y * 64;
    const int tid = threadIdx.x;
    const int r = tid >> 4;
    const int c4 = (tid & 15) * 4;
    #pragma unroll
    for (int p = 0; p < 4; ++p) {
        int o = p * 16 + r;
        ushort4 v = *(const ushort4*)(src + (size_t)(o0 + o) * 1024 + t0 + c4);
        sm[o][c4 + 0] = v.x; sm[o][c4 + 1] = v.y;
        sm[o][c4 + 2] = v.z; sm[o][c4 + 3] = v.w;
    }
    __syncthreads();
    #pragma unroll
    for (int p = 0; p < 4; ++p) {
        int t = p * 16 + r;
        int tg = t0 + t;
        ushort4 v;
        if (tg < 1016) {
            v.x = sm[c4 + 0][t]; v.y = sm[c4 + 1][t];
            v.z = sm[c4 + 2][t]; v.w = sm[c4 + 3][t];
        } else {
            v.x = 0; v.y = 0; v.z = 0; v.w = 0;
        }
        *(ushort4*)(dst + (size_t)tg * 2048 + o0 + c4) = v;
    }
}

// ---------------- MFMA GEMM, direct-global fragments ----------------
// D[m][n] = sum_k A[m][k] * B[n][k]   (both operands row-major, 8-contig-K per lane)
// MODE 0 (T-form):  out bf16 condBT[m*2048+n], bias[n]
// MODE 1 (N-form):  out f32  cond_acts[m*1016+n] (n<1016), bias[m]
template<int MODE>
__global__ __launch_bounds__(256) void gemm_mfma(
    const unsigned short* __restrict__ A, const unsigned short* __restrict__ Bm,
    const float* __restrict__ bias, void* __restrict__ outp,
    int ldA, int ldB, int K)
{
    const int w = threadIdx.x >> 6, lane = threadIdx.x & 63;
    const int m0 = blockIdx.y * 128 + (w >> 1) * 64;
    const int n0 = blockIdx.x * 128 + (w & 1) * 64;
    const int row = lane & 15, g = lane >> 4;

    f32x4 acc[4][4];
    #pragma unroll
    for (int i = 0; i < 4; ++i)
        #pragma unroll
        for (int j = 0; j < 4; ++j) acc[i][j] = (f32x4){0.f, 0.f, 0.f, 0.f};

    const unsigned short* Ap = A + (size_t)(m0 + row) * ldA + g * 8;
    const unsigned short* Bp = Bm + (size_t)(n0 + row) * ldB + g * 8;

    for (int kk = 0; kk < K; kk += 32) {
        bf16x8 af[4], bf[4];
        #pragma unroll
        for (int fm = 0; fm < 4; ++fm)
            af[fm] = *(const bf16x8*)(Ap + (size_t)fm * 16 * ldA + kk);
        #pragma unroll
        for (int fn = 0; fn < 4; ++fn)
            bf[fn] = *(const bf16x8*)(Bp + (size_t)fn * 16 * ldB + kk);
        #pragma unroll
        for (int fm = 0; fm < 4; ++fm)
            #pragma unroll
            for (int fn = 0; fn < 4; ++fn)
                acc[fm][fn] = __builtin_amdgcn_mfma_f32_16x16x32_bf16(af[fm], bf[fn], acc[fm][fn], 0, 0, 0);
    }

    #pragma unroll
    for (int fm = 0; fm < 4; ++fm) {
        #pragma unroll
        for (int fn = 0; fn < 4; ++fn) {
            const int n_g = n0 + fn * 16 + row;
            const int m_b = m0 + fm * 16 + g * 4;
            if (MODE == 0) {
                unsigned short* o = (unsigned short*)outp;
                const float bb = bias[n_g];
                #pragma unroll
                for (int r = 0; r < 4; ++r) {
                    float v = F4C(acc[fm][fn], r) + bb;
                    o[(size_t)(m_b + r) * 2048 + n_g] = (unsigned short)pk_bf16(v, v);
                }
            } else {
                float* o = (float*)outp;
                if (n_g < 1016) {
                    #pragma unroll
                    for (int r = 0; r < 4; ++r) {
                        float v = F4C(acc[fm][fn], r) + bias[m_b + r];
                        o[(size_t)(m_b + r) * 1016 + n_g] = v;
                    }
                }
            }
        }
    }
}

// ---------------- Generic fp32 GEMM (final small layers) ----------------
template<bool RELU_IN, bool RELU_OUT, bool SHIFT>
__global__ __launch_bounds__(256) void gemm_f32(
    const float* __restrict__ W, const float* __restrict__ X,
    const float* __restrict__ bias, float* __restrict__ Y,
    int M, int K, int N)
{
    __shared__ float ws_s[16][68];
    __shared__ float xs_s[16][68];
    const int m0 = blockIdx.y * 64;
    const int n0 = blockIdx.x * 64;
    const int tid = threadIdx.x;
    const int tx = tid & 15, ty = tid >> 4;

    float acc[4][4];
    #pragma unroll
    for (int i = 0; i < 4; ++i)
        #pragma unroll
        for (int j = 0; j < 4; ++j) acc[i][j] = 0.f;

    for (int kk = 0; kk < K; kk += 16) {
        {
            int m = tid >> 2;
            int k4 = (tid & 3) * 4;
            float4 v = *(const float4*)&W[(size_t)(m0 + m) * K + kk + k4];
            ws_s[k4 + 0][m] = v.x; ws_s[k4 + 1][m] = v.y;
            ws_s[k4 + 2][m] = v.z; ws_s[k4 + 3][m] = v.w;
        }
        {
            int k = tid >> 4;
            int n4 = (tid & 15) * 4;
            int n = n0 + n4;
            float4 v;
            if (n + 3 < N) v = *(const float4*)&X[(size_t)(kk + k) * N + n];
            else {
                v.x = (n + 0 < N) ? X[(size_t)(kk + k) * N + n + 0] : 0.f;
                v.y = (n + 1 < N) ? X[(size_t)(kk + k) * N + n + 1] : 0.f;
                v.z = (n + 2 < N) ? X[(size_t)(kk + k) * N + n + 2] : 0.f;
                v.w = (n + 3 < N) ? X[(size_t)(kk + k) * N + n + 3] : 0.f;
            }
            if (RELU_IN) {
                v.x = fmaxf(v.x, 0.f); v.y = fmaxf(v.y, 0.f);
                v.z = fmaxf(v.z, 0.f); v.w = fmaxf(v.w, 0.f);
            }
            *(float4*)&xs_s[k][n4] = v;
        }
        __syncthreads();
        #pragma unroll
        for (int k = 0; k < 16; ++k) {
            float a[4], b[4];
            #pragma unroll
            for (int i = 0; i < 4; ++i) a[i] = ws_s[k][ty * 4 + i];
            #pragma unroll
            for (int j = 0; j < 4; ++j) b[j] = xs_s[k][tx * 4 + j];
            #pragma unroll
            for (int i = 0; i < 4; ++i)
                #pragma unroll
                for (int j = 0; j < 4; ++j) acc[i][j] += a[i] * b[j];
        }
        __syncthreads();
    }
    #pragma unroll
    for (int i = 0; i < 4; ++i) {
        int m = m0 + ty * 4 + i;
        float bb = bias ? bias[m] : 0.f;
        #pragma unroll
        for (int j = 0; j < 4; ++j) {
            int n = n0 + tx * 4 + j;
            float v = acc[i][j] + bb;
            if (RELU_OUT) v = fmaxf(v, 0.f);
            if (!SHIFT) {
                if (n < N) Y[(size_t)m * N + n] = v;
            } else {
                if (n == 0) Y[(size_t)m * N] = 0.f;
                if (n + 1 < N) Y[(size_t)m * N + n + 1] = v;
            }
        }
    }
}

// ---------------- Layer kernel: dilated gated conv + res + skip ----------------
__global__ __launch_bounds__(256) void k_layer(
    const float* __restrict__ x_in,
    float* __restrict__ x_out,
    const float* __restrict__ cond,
    const float* __restrict__ w_dil,
    const float* __restrict__ b_dil,
    const float* __restrict__ w_res,
    const float* __restrict__ b_res,
    const float* __restrict__ w_skip,
    const float* __restrict__ b_skip,
    float* __restrict__ skip_acc,
    int d, int first, int last)
{
    __shared__ float xs[64 * 136];
    __shared__ float ia_s[128 * 9];
    __shared__ float acts_s[64 * 9];
    const int tid = threadIdx.x;
    const int t0 = blockIdx.x * 8;
    const int w = 8 + d;

    int count = 64 * w;
    for (int idx = tid; idx < count; idx += 256) {
        int c = idx / w, tt = idx - c * w;
        int tg = t0 - d + tt;
        xs[idx] = (tg >= 0) ? x_in[(size_t)c * T_LEN + tg] : 0.f;
    }
    __syncthreads();

    {
        int o = tid & 127;
        int tq = tid >> 7;
        float ia[4];
        #pragma unroll
        for (int s = 0; s < 4; ++s) {
            int t = tq + 2 * s;
            ia[s] = b_dil[o] + cond[(size_t)o * T_LEN + t0 + t];
        }
        const float* wd = w_dil + (size_t)o * 128;
        for (int c = 0; c < 64; ++c) {
            float w0 = wd[c * 2], w1 = wd[c * 2 + 1];
            const float* xr = xs + c * w;
            #pragma unroll
            for (int s = 0; s < 4; ++s) {
                int t = tq + 2 * s;
                ia[s] += w0 * xr[t] + w1 * xr[t + d];
            }
        }
        #pragma unroll
        for (int s = 0; s < 4; ++s) {
            int t = tq + 2 * s;
            ia_s[o * 9 + t] = ia[s];
        }
    }
    __syncthreads();

    #pragma unroll
    for (int rep = 0; rep < 2; ++rep) {
        int idx = tid + rep * 256;
        int c = idx >> 3, t = idx & 7;
        float a = ia_s[c * 9 + t];
        float gg = ia_s[(c + 64) * 9 + t];
        acts_s[c * 9 + t] = tanhf(a) * (1.f / (1.f + expf(-gg)));
    }
    __syncthreads();

    {
        int o = tid;
        float acc[8];
        #pragma unroll
        for (int t = 0; t < 8; ++t) acc[t] = 0.f;
        const float* wk = w_skip + (size_t)o * 64;
        for (int c = 0; c < 64; ++c) {
            float wv = wk[c];
            #pragma unroll
            for (int t = 0; t < 8; ++t) acc[t] += wv * acts_s[c * 9 + t];
        }
        float bb = b_skip[o];
        #pragma unroll
        for (int t = 0; t < 8; ++t) {
            size_t oidx = (size_t)o * T_LEN + t0 + t;
            float prev = first ? 0.f : skip_acc[oidx];
            skip_acc[oidx] = prev + acc[t] + bb;
        }
    }

    if (!last) {
        #pragma unroll
        for (int rep = 0; rep < 2; ++rep) {
            int idx = tid + rep * 256;
            int c = idx >> 3, t = idx & 7;
            float r = b_res[c];
            const float* wr = w_res + (size_t)c * 64;
            for (int cc = 0; cc < 64; ++cc) r += wr[cc] * acts_s[cc * 9 + t];
            x_out[(size_t)c * T_LEN + t0 + t] = r + xs[c * w + t + d];
        }
    }
}

// ---------------- host launch ----------------
extern "C" void kernel_launch(void* const* d_in, const int* in_sizes, int n_in,
                              void* d_out, int out_size, void* d_ws, size_t ws_size,
                              hipStream_t stream)
{
    const float* features = (const float*)d_in[0];
    const float* audio    = (const float*)d_in[1];
    const float* w_up     = (const float*)d_in[2];
    const float* b_up     = (const float*)d_in[3];
    const float* w_cond   = (const float*)d_in[4];
    const float* b_cond   = (const float*)d_in[5];
    const float* embed    = (const float*)d_in[6];
    const float* w_dil    = (const float*)d_in[7];
    const float* b_dil    = (const float*)d_in[8];
    const float* w_res    = (const float*)d_in[9];
    const float* b_res    = (const float*)d_in[10];
    const float* w_skip   = (const float*)d_in[11];
    const float* b_skip   = (const float*)d_in[12];
    const float* w_out    = (const float*)d_in[13];
    const float* w_end    = (const float*)d_in[14];
    float* out = (float*)d_out;

    char* base = (char*)d_ws;
    unsigned short* w_cond_b  = (unsigned short*)(base);              // 8 MB
    unsigned short* f2t       = (unsigned short*)(base + 8388608);    // 1 MB
    unsigned short* cond0     = (unsigned short*)(base + 9437184);    // 4 MB
    unsigned short* cond0T    = (unsigned short*)(base + 13631488);   // 4 MB
    unsigned short* condBT    = (unsigned short*)(base + 17825792);   // 4 MB
    float*          cond_acts = (float*)(base + 22020096);            // 8.3 MB
    float*          x0        = (float*)(base + 30343168);
    float*          x1        = (float*)(base + 30603264);
    float*          skip      = (float*)(base + 30863360);
    float*          h2        = (float*)(base + 31903744);

    // 1. mu-law + q + embedding
    k_mulaw_embed<<<4, 256, 0, stream>>>(audio, embed, x0, out + 260096);
    // 2. prep: w_cond -> bf16; features -> interleaved F2T
    k_cvt_bf16<<<4096, 256, 0, stream>>>(w_cond, w_cond_b);
    k_build_f2t<<<128, 256, 0, stream>>>(features, f2t);
    // 3. MFMA upsample -> cond0 bf16 [2048][1024]
    k_upsample_mfma<<<256, 256, 0, stream>>>(f2t, w_up, b_up, cond0);
    // 4. transpose -> cond0T [1024][2048]
    k_transpose_bf16<<<dim3(16, 32), 256, 0, stream>>>(cond0, cond0T);
    // 5. G1 (T-form): condBT[t][oc] = cond0T . w_cond^T + b_cond
    gemm_mfma<0><<<dim3(16, 8), 256, 0, stream>>>(cond0T, w_cond_b, b_cond, condBT, 2048, 2048, 2048);
    // 6. G2 (N-form): cond_acts[oc][t] = w_cond . condB + b_cond
    gemm_mfma<1><<<dim3(8, 16), 256, 0, stream>>>(w_cond_b, condBT, b_cond, cond_acts, 2048, 2048, 2048);

    // 7. 16 WaveNet layers (sequential)
    float* xbuf[2] = {x0, x1};
    for (int i = 0; i < 16; ++i) {
        int d = 1 << (i & 7);
        k_layer<<<127, 256, 0, stream>>>(
            xbuf[i & 1], xbuf[(i + 1) & 1],
            cond_acts + (size_t)i * 128 * T_LEN,
            w_dil + (size_t)i * 16384, b_dil + i * 128,
            (i < 15) ? (w_res + (size_t)i * 4096) : (const float*)nullptr,
            (i < 15) ? (b_res + i * 64) : (const float*)nullptr,
            w_skip + (size_t)i * 16384, b_skip + i * 256,
            skip, d, (i == 0) ? 1 : 0, (i == 15) ? 1 : 0);
    }

    // 8. h2 = relu(w_out @ relu(skip))
    gemm_f32<true, true, false><<<dim3(16, 4), 256, 0, stream>>>(
        w_out, skip, nullptr, h2, 256, 256, T_LEN);
    // 9. out = shift(w_end @ h2)
    gemm_f32<false, false, true><<<dim3(16, 4), 256, 0, stream>>>(
        w_end, h2, nullptr, out, 256, 256, T_LEN);
}